// Round 1
// baseline (41691.589 us; speedup 1.0000x reference)
//
#include <hip/hip_runtime.h>
#include <math.h>

#define NB 1024
#define NS 76
#define SSA 34
#define SSB 28
#define SSP 14
#define DM 512
#define NH 8
#define DH 64
#define NE 16
#define CAP 19
#define NSLOT (NB*CAP)   // 19456 slots per (expert,rank) list

__device__ __forceinline__ float gelu_tanh(float x) {
  float x3 = x*x*x;
  return 0.5f*x*(1.0f + tanhf(0.7978845608028654f*(x + 0.044715f*x3)));
}

// ---------------- embedding + sinusoidal PE ----------------
__global__ __launch_bounds__(256) void k_embed(
    const int* __restrict__ ta, const int* __restrict__ tb, const int* __restrict__ tp,
    const float* __restrict__ Wa, const float* __restrict__ Wb, const float* __restrict__ Wp,
    float* __restrict__ X) {
  int idx = blockIdx.x * 256 + threadIdx.x;
  if (idx >= NB*NS*DM) return;
  int d = idx & (DM-1);
  int bs = idx >> 9;
  int s = bs % NS, b = bs / NS;
  int sl, tok; const float* W;
  if (s < SSA)          { sl = s;         tok = ta[b*SSA+sl]; W = Wa; }
  else if (s < SSA+SSB) { sl = s-SSA;     tok = tb[b*SSB+sl]; W = Wb; }
  else                  { sl = s-SSA-SSB; tok = tp[b*SSP+sl]; W = Wp; }
  float dv = expf((float)(d & ~1) * (-9.210340371976184f/512.0f));
  float ang = (float)sl * dv;
  float pe = (d & 1) ? cosf(ang) : sinf(ang);
  X[idx] = W[(size_t)tok*DM + d] + pe;
}

// ---------------- fused MHA per (b, head): in-block QKV + softmax + PV ----------------
// Writes O (pre-output-proj) into T[b, seg_off+s, h*64+d].
__global__ __launch_bounds__(512) void k_attn(
    const float* __restrict__ X, const float* __restrict__ AW,
    float* __restrict__ O, int enc, int seg_off, int seg_len) {
  __shared__ float Xs[NS][128];
  __shared__ float Qs[NS][65], Ks[NS][65], Vs[NS][65];
  __shared__ float pbuf[8][128];
  int b = blockIdx.x, h = blockIdx.y;
  int t = threadIdx.x, w = t >> 6, lane = t & 63;
  const float* Wq = AW + (size_t)(enc*4+0)*DM*DM + h*DH;
  const float* Wk = AW + (size_t)(enc*4+1)*DM*DM + h*DH;
  const float* Wv = AW + (size_t)(enc*4+2)*DM*DM + h*DH;

  float aq[10], ak[10], av[10];
#pragma unroll
  for (int i=0;i<10;i++){ aq[i]=0.f; ak[i]=0.f; av[i]=0.f; }

  for (int ch=0; ch<4; ch++) {
    for (int e = t; e < NS*128; e += 512) {
      int r = e >> 7, c = e & 127;
      Xs[r][c] = (r < seg_len) ? X[((size_t)b*NS + seg_off + r)*DM + ch*128 + c] : 0.f;
    }
    __syncthreads();
    for (int k=0;k<128;k++) {
      int kk = ch*128 + k;
      float wq = Wq[(size_t)kk*DM + lane];
      float wk = Wk[(size_t)kk*DM + lane];
      float wv = Wv[(size_t)kk*DM + lane];
#pragma unroll
      for (int i=0;i<10;i++) {
        int s = w + 8*i;
        if (s < seg_len) {
          float x = Xs[s][k];
          aq[i] += x*wq; ak[i] += x*wk; av[i] += x*wv;
        }
      }
    }
    __syncthreads();
  }
#pragma unroll
  for (int i=0;i<10;i++) {
    int s = w + 8*i;
    if (s < seg_len) { Qs[s][lane]=aq[i]; Ks[s][lane]=ak[i]; Vs[s][lane]=av[i]; }
  }
  __syncthreads();

#pragma unroll 1
  for (int i0=0;i0<10;i0++) {
    int qi = w + 8*i0;
    if (qi >= seg_len) continue;
    float s1 = -1e30f, s2 = -1e30f;
    int j2 = lane + 64;
    {
      float acc = 0.f;
#pragma unroll
      for (int d=0; d<DH; d++) acc += Qs[qi][d]*Ks[lane][d];
      if (lane < seg_len) s1 = acc*0.125f;
    }
    if (j2 < seg_len) {
      float acc = 0.f;
#pragma unroll
      for (int d=0; d<DH; d++) acc += Qs[qi][d]*Ks[j2][d];
      s2 = acc*0.125f;
    }
    float m = fmaxf(s1, s2);
#pragma unroll
    for (int o=32;o;o>>=1) m = fmaxf(m, __shfl_xor(m, o));
    float p1 = (lane < seg_len) ? expf(s1 - m) : 0.f;
    float p2 = (j2  < seg_len) ? expf(s2 - m) : 0.f;
    float l = p1 + p2;
#pragma unroll
    for (int o=32;o;o>>=1) l += __shfl_xor(l, o);
    float inv = 1.f / l;
    pbuf[w][lane] = p1*inv;
    pbuf[w][lane+64] = p2*inv;
    float o = 0.f;
    for (int j=0;j<seg_len;j++) o += pbuf[w][j]*Vs[j][lane];
    O[((size_t)b*NS + seg_off + qi)*DM + h*DH + lane] = o;
  }
}

// ---------------- generic tiled fp32 GEMM: C[g(m)][n] = sum_k A[g(m)][k]*W[k][n] ----------------
// g(m) = roff + (m/rpg)*pitch + m%rpg   (segment row mapping; identity when rpg>=M)
__global__ __launch_bounds__(256) void k_gemm(
    const float* __restrict__ A, const float* __restrict__ W, float* __restrict__ C,
    int M, int N, int K, int lda, int ldc, int rpg, int pitch, int roff) {
  __shared__ float As[16][68];
  __shared__ float Bs[16][68];
  int tid = threadIdx.x;
  int tx = tid & 15, ty = tid >> 4;
  int m0 = blockIdx.x * 64, n0 = blockIdx.y * 64;
  int garow[4], gcrow[4];
#pragma unroll
  for (int i=0;i<4;i++) {
    int e = tid + i*256;
    int m = m0 + (e >> 4);
    garow[i] = roff + (m / rpg) * pitch + (m % rpg);
  }
#pragma unroll
  for (int i=0;i<4;i++) {
    int m = m0 + ty*4 + i;
    gcrow[i] = roff + (m / rpg) * pitch + (m % rpg);
  }
  float acc[4][4] = {};
  for (int k0=0;k0<K;k0+=16) {
#pragma unroll
    for (int i=0;i<4;i++) {
      int e = tid + i*256;
      As[e & 15][e >> 4] = A[(size_t)garow[i]*lda + k0 + (e & 15)];
    }
#pragma unroll
    for (int i=0;i<4;i++) {
      int e = tid + i*256;
      int kk = e >> 6, n = e & 63;
      int gn = n0 + n;
      Bs[kk][n] = (gn < N) ? W[(size_t)(k0 + kk)*N + gn] : 0.f;
    }
    __syncthreads();
#pragma unroll
    for (int kk=0;kk<16;kk++) {
      float a[4], bb[4];
#pragma unroll
      for (int i=0;i<4;i++) a[i] = As[kk][ty*4+i];
#pragma unroll
      for (int j=0;j<4;j++) bb[j] = Bs[kk][tx*4+j];
#pragma unroll
      for (int i=0;i<4;i++)
#pragma unroll
        for (int j=0;j<4;j++) acc[i][j] += a[i]*bb[j];
    }
    __syncthreads();
  }
#pragma unroll
  for (int i=0;i<4;i++)
#pragma unroll
    for (int j=0;j<4;j++) {
      int gn = n0 + tx*4 + j;
      if (gn < N) C[(size_t)gcrow[i]*ldc + gn] = acc[i][j];
    }
}

// ---------------- residual add + RMSNorm (D=512), in-place into X ----------------
__global__ __launch_bounds__(256) void k_addnorm(
    float* __restrict__ X, const float* __restrict__ U, const float* __restrict__ w) {
  int r = blockIdx.x, t = threadIdx.x;
  size_t base = (size_t)r*DM;
  float v0 = X[base+t] + U[base+t];
  float v1 = X[base+t+256] + U[base+t+256];
  float ss = v0*v0 + v1*v1;
#pragma unroll
  for (int o=32;o;o>>=1) ss += __shfl_xor(ss, o);
  __shared__ float red[4];
  if ((t & 63) == 0) red[t>>6] = ss;
  __syncthreads();
  float tot = red[0]+red[1]+red[2]+red[3];
  float sc = rsqrtf(tot * (1.f/512.f) + 1e-6f);
  X[base+t] = v0*sc*w[t];
  X[base+t+256] = v1*sc*w[t+256];
}

// ---------------- MoE routing: top-2 gating + capacity cumsum, per batch row ----------------
__global__ __launch_bounds__(256) void k_route(
    const float* __restrict__ X, const float* __restrict__ Wg,
    int* __restrict__ rec_src, float* __restrict__ rec_gain, int* __restrict__ cnt) {
  __shared__ float gl[NS][NE];
  __shared__ float g1s[NS], g2s[NS];
  __shared__ int i1s[NS], i2s[NS];
  int b = blockIdx.x, t = threadIdx.x;
  for (int e0 = t; e0 < NS*NE; e0 += 256) {
    int s = e0 >> 4, ee = e0 & 15;
    const float* xr = X + ((size_t)b*NS + s)*DM;
    float acc = 0.f;
    for (int k=0;k<DM;k++) acc += xr[k]*Wg[k*NE+ee];
    gl[s][ee] = acc;
  }
  __syncthreads();
  if (t < NS) {
    float mx = -1e30f;
#pragma unroll
    for (int e=0;e<NE;e++) mx = fmaxf(mx, gl[t][e]);
    float sum = 0.f;
#pragma unroll
    for (int e=0;e<NE;e++) sum += expf(gl[t][e]-mx);
    int i1 = 0; float l1 = gl[t][0];
#pragma unroll
    for (int e=1;e<NE;e++) if (gl[t][e] > l1) { l1 = gl[t][e]; i1 = e; }
    int i2 = -1; float l2 = -1e30f;
#pragma unroll
    for (int e=0;e<NE;e++) if (e != i1 && gl[t][e] > l2) { l2 = gl[t][e]; i2 = e; }
    float g1 = expf(l1-mx)/sum, g2 = expf(l2-mx)/sum;
    float den = g1 + g2 + 1e-9f;
    g1s[t] = g1/den; g2s[t] = g2/den;
    i1s[t] = i1; i2s[t] = i2;
  }
  __syncthreads();
  if (t == 0) {
    int n1[NE], n2[NE], c1[NE];
    for (int e=0;e<NE;e++) { n1[e]=0; n2[e]=0; }
    for (int s=0;s<NS;s++) {
      int e = i1s[s]; int p = n1[e]++;
      if (p < CAP) {
        int idx = atomicAdd(&cnt[e*2+0], 1);
        rec_src[(size_t)(e*2+0)*NSLOT + idx] = b*NS + s;
        rec_gain[(size_t)(e*2+0)*NSLOT + idx] = g1s[s];
      }
    }
    for (int e=0;e<NE;e++) c1[e] = n1[e] < CAP ? n1[e] : CAP;
    for (int s=0;s<NS;s++) {
      int e = i2s[s]; int p = c1[e] + n2[e]++;
      if (p < CAP) {
        int idx = atomicAdd(&cnt[e*2+1], 1);
        rec_src[(size_t)(e*2+1)*NSLOT + idx] = b*NS + s;
        rec_gain[(size_t)(e*2+1)*NSLOT + idx] = g2s[s];
      }
    }
  }
}

// ---------------- expert MLP over compacted dispatch rows, scatter into T (residual) ----------------
__global__ __launch_bounds__(256) void k_expert(
    const float* __restrict__ X, const float* __restrict__ W1,
    const float* __restrict__ W2, float* __restrict__ T,
    const int* __restrict__ rec_src, const float* __restrict__ rec_gain,
    const int* __restrict__ cnt, int rank) {
  int e = blockIdx.y;
  int l = e*2 + rank;
  int n = cnt[l];
  int r0 = blockIdx.x * 32;
  if (r0 >= n) return;
  __shared__ float Xs[32][DM];
  __shared__ int srcs[32];
  __shared__ float gains[32];
  int t = threadIdx.x;
  if (t < 32) {
    int rr = r0 + t;
    srcs[t]  = (rr < n) ? rec_src [(size_t)l*NSLOT + rr] : -1;
    gains[t] = (rr < n) ? rec_gain[(size_t)l*NSLOT + rr] : 0.f;
  }
  __syncthreads();
  for (int r=0;r<32;r++) {
    int src = srcs[r];
    float v0 = 0.f, v1 = 0.f;
    if (src >= 0) {
      v0 = X[(size_t)src*DM + t];
      v1 = X[(size_t)src*DM + t + 256];
    }
    Xs[r][t] = v0; Xs[r][t+256] = v1;
  }
  __syncthreads();
  const float* w1 = W1 + (size_t)e*DM*DM;
  float a0[32], a1[32];
#pragma unroll
  for (int r=0;r<32;r++){a0[r]=0.f;a1[r]=0.f;}
  for (int k0=0;k0<DM;k0+=4) {
    float wa[4], wb[4];
#pragma unroll
    for (int q=0;q<4;q++) { wa[q] = w1[(size_t)(k0+q)*DM + t]; wb[q] = w1[(size_t)(k0+q)*DM + t+256]; }
#pragma unroll
    for (int r=0;r<32;r++) {
      float4 x = *reinterpret_cast<const float4*>(&Xs[r][k0]);
      a0[r] += x.x*wa[0] + x.y*wa[1] + x.z*wa[2] + x.w*wa[3];
      a1[r] += x.x*wb[0] + x.y*wb[1] + x.z*wb[2] + x.w*wb[3];
    }
  }
  __syncthreads();
#pragma unroll
  for (int r=0;r<32;r++) {
    Xs[r][t]     = gelu_tanh(a0[r]);
    Xs[r][t+256] = gelu_tanh(a1[r]);
  }
  __syncthreads();
  const float* w2 = W2 + (size_t)e*DM*DM;
#pragma unroll
  for (int r=0;r<32;r++){a0[r]=0.f;a1[r]=0.f;}
  for (int k0=0;k0<DM;k0+=4) {
    float wa[4], wb[4];
#pragma unroll
    for (int q=0;q<4;q++) { wa[q] = w2[(size_t)(k0+q)*DM + t]; wb[q] = w2[(size_t)(k0+q)*DM + t+256]; }
#pragma unroll
    for (int r=0;r<32;r++) {
      float4 x = *reinterpret_cast<const float4*>(&Xs[r][k0]);
      a0[r] += x.x*wa[0] + x.y*wa[1] + x.z*wa[2] + x.w*wa[3];
      a1[r] += x.x*wb[0] + x.y*wb[1] + x.z*wb[2] + x.w*wb[3];
    }
  }
  for (int r=0;r<32;r++) {
    int src = srcs[r];
    if (src >= 0) {
      float g = gains[r];
      size_t base = (size_t)src*DM;
      T[base+t]     += g*a0[r];
      T[base+t+256] += g*a1[r];
    }
  }
}

// ---------------- classifier epilogue kernels ----------------
__global__ __launch_bounds__(256) void k_h1norm(
    float* __restrict__ H, const float* __restrict__ bias, const float* __restrict__ w) {
  int r = blockIdx.x, t = threadIdx.x;
  size_t base = (size_t)r*1000;
  float v[4]; float ss = 0.f;
#pragma unroll
  for (int i=0;i<4;i++) {
    int c = t + i*256;
    float x = 0.f;
    if (c < 1000) { x = fmaxf(H[base+c] + bias[c], 0.f); }
    v[i] = x; ss += x*x;
  }
#pragma unroll
  for (int o=32;o;o>>=1) ss += __shfl_xor(ss, o);
  __shared__ float red[4];
  if ((t & 63) == 0) red[t>>6] = ss;
  __syncthreads();
  float tot = red[0]+red[1]+red[2]+red[3];
  float sc = rsqrtf(tot * 0.001f + 1e-6f);
#pragma unroll
  for (int i=0;i<4;i++) {
    int c = t + i*256;
    if (c < 1000) H[base+c] = v[i]*sc*w[c];
  }
}

__global__ __launch_bounds__(128) void k_h2(
    const float* __restrict__ H1, const float* __restrict__ W2c,
    const float* __restrict__ b2, const float* __restrict__ rms2,
    float* __restrict__ H2) {
  __shared__ float hrow[1000];
  __shared__ float sq[128];
  int r = blockIdx.x, t = threadIdx.x;
  for (int c=t;c<1000;c+=128) hrow[c] = H1[(size_t)r*1000+c];
  __syncthreads();
  float acc = 0.f;
  if (t < 100) {
    for (int k=0;k<1000;k++) acc += hrow[k]*W2c[k*100+t];
    acc = fmaxf(acc + b2[t], 0.f);
  }
  sq[t] = (t<100)? acc*acc : 0.f;
  __syncthreads();
  if (t < 64) sq[t] += sq[t+64];
  __syncthreads();
  if (t == 0) { float s=0.f; for (int i=0;i<64;i++) s+=sq[i]; sq[0]=s; }
  __syncthreads();
  float sc = rsqrtf(sq[0]*0.01f + 1e-6f);
  if (t < 100) H2[(size_t)r*100+t] = acc*sc*rms2[t];
}

__global__ __launch_bounds__(256) void k_out(
    const float* __restrict__ H2, const float* __restrict__ w3,
    const float* __restrict__ b3, float* __restrict__ out) {
  int b = blockIdx.x*256 + threadIdx.x;
  if (b >= NB) return;
  float acc = b3[0];
  for (int k=0;k<100;k++) acc += H2[(size_t)b*100+k]*w3[k];
  out[b] = acc;
}

extern "C" void kernel_launch(void* const* d_in, const int* in_sizes, int n_in,
                              void* d_out, int out_size, void* d_ws, size_t ws_size,
                              hipStream_t stream) {
  const int*   ta   = (const int*)d_in[0];
  const int*   tb   = (const int*)d_in[1];
  const int*   tp   = (const int*)d_in[2];
  const float* Wa   = (const float*)d_in[3];
  const float* Wb   = (const float*)d_in[4];
  const float* Wp   = (const float*)d_in[5];
  const float* AW   = (const float*)d_in[6];
  const float* rmsd = (const float*)d_in[7];
  const float* Wg   = (const float*)d_in[8];
  const float* W1   = (const float*)d_in[9];
  const float* W2   = (const float*)d_in[10];
  const float* cw1  = (const float*)d_in[11];
  const float* cb1  = (const float*)d_in[12];
  const float* rms1 = (const float*)d_in[13];
  const float* cw2  = (const float*)d_in[14];
  const float* cb2  = (const float*)d_in[15];
  const float* rms2 = (const float*)d_in[16];
  const float* cw3  = (const float*)d_in[17];
  const float* cb3  = (const float*)d_in[18];
  float* out = (float*)d_out;

  char* ws = (char*)d_ws;
  size_t SZ = (size_t)NB*NS*DM*sizeof(float);      // 159,383,552 B
  float* X = (float*)(ws);
  float* T = (float*)(ws + SZ);
  float* U = (float*)(ws + 2*SZ);
  size_t off = 3*SZ;
  int*   rec_src  = (int*)  (ws + off); off += (size_t)NE*2*NSLOT*sizeof(int);
  float* rec_gain = (float*)(ws + off); off += (size_t)NE*2*NSLOT*sizeof(float);
  int*   cnt      = (int*)  (ws + off); off += 256;
  float* h1 = U;                                   // reuse U for classifier h1 [1024,1000]
  float* h2 = (float*)(ws + off);                  // [1024,100]

  // 1. embedding + PE -> X
  k_embed<<<dim3((NB*NS*DM+255)/256), dim3(256), 0, stream>>>(ta,tb,tp,Wa,Wb,Wp,X);

  // 2. per-branch encoders: attention -> T, O-proj -> U, add+rmsnorm -> X
  k_attn<<<dim3(NB,NH),512,0,stream>>>(X, AW, T, 0, 0,        SSA);
  k_attn<<<dim3(NB,NH),512,0,stream>>>(X, AW, T, 1, SSA,      SSB);
  k_attn<<<dim3(NB,NH),512,0,stream>>>(X, AW, T, 2, SSA+SSB,  SSP);
  k_gemm<<<dim3(NB*SSA/64, 8),256,0,stream>>>(T, AW+(size_t)(0*4+3)*DM*DM, U, NB*SSA, DM, DM, DM, DM, SSA, NS, 0);
  k_gemm<<<dim3(NB*SSB/64, 8),256,0,stream>>>(T, AW+(size_t)(1*4+3)*DM*DM, U, NB*SSB, DM, DM, DM, DM, SSB, NS, SSA);
  k_gemm<<<dim3(NB*SSP/64, 8),256,0,stream>>>(T, AW+(size_t)(2*4+3)*DM*DM, U, NB*SSP, DM, DM, DM, DM, SSP, NS, SSA+SSB);
  k_addnorm<<<NB*NS,256,0,stream>>>(X, U, rmsd);

  // 3. full-sequence encoder
  k_attn<<<dim3(NB,NH),512,0,stream>>>(X, AW, T, 3, 0, NS);
  k_gemm<<<dim3(NB*NS/64, 8),256,0,stream>>>(T, AW+(size_t)(3*4+3)*DM*DM, U, NB*NS, DM, DM, DM, DM, NS, NS, 0);
  k_addnorm<<<NB*NS,256,0,stream>>>(X, U, rmsd);

  // 4. MoE: route -> compact lists, T = X (residual), scatter rank-1 then rank-2
  hipMemsetAsync(cnt, 0, NE*2*sizeof(int), stream);
  k_route<<<NB,256,0,stream>>>(X, Wg, rec_src, rec_gain, cnt);
  hipMemcpyAsync(T, X, SZ, hipMemcpyDeviceToDevice, stream);
  k_expert<<<dim3((NSLOT+31)/32, NE),256,0,stream>>>(X, W1, W2, T, rec_src, rec_gain, cnt, 0);
  k_expert<<<dim3((NSLOT+31)/32, NE),256,0,stream>>>(X, W1, W2, T, rec_src, rec_gain, cnt, 1);

  // 5. classifier: T flat [1024, 38912] @ cls_w1 -> h1; norm; h2; out
  k_gemm<<<dim3(NB/64, (1000+63)/64),256,0,stream>>>(T, cw1, h1, NB, 1000, NS*DM, NS*DM, 1000, NB, 0, 0);
  k_h1norm<<<NB,256,0,stream>>>(h1, cb1, rms1);
  k_h2<<<NB,128,0,stream>>>(h1, cw2, cb2, rms2, h2);
  k_out<<<dim3((NB+255)/256),256,0,stream>>>(h2, cw3, cb3, out);
}

// Round 4
// 10230.422 us; speedup vs baseline: 4.0753x; 4.0753x over previous
//
#include <hip/hip_runtime.h>
#include <math.h>

#define NB 1024
#define NS 76
#define SSA 34
#define SSB 28
#define SSP 14
#define DM 512
#define NH 8
#define DH 64
#define NE 16
#define CAP 19
#define NSLOT (NB*CAP)

typedef unsigned short ushortt;
typedef short s16x4 __attribute__((ext_vector_type(4)));
typedef short s16x8 __attribute__((ext_vector_type(8)));
typedef float f32x4 __attribute__((ext_vector_type(4)));

__device__ __forceinline__ ushortt f2bf(float f) {
  union { float f; unsigned int u; } v; v.f = f;
  unsigned int u = v.u;
  u += 0x7fffu + ((u >> 16) & 1u);
  return (ushortt)(u >> 16);
}
__device__ __forceinline__ float bf2f(ushortt s) {
  union { unsigned int u; float f; } v; v.u = ((unsigned int)s) << 16;
  return v.f;
}
// returns lo<<16 | hi  (hi = bf16(v), lo = bf16(v - hi))
__device__ __forceinline__ unsigned int split_bf(float v) {
  ushortt h = f2bf(v);
  float r = v - bf2f(h);
  ushortt l = f2bf(r);
  return ((unsigned int)l << 16) | (unsigned int)h;
}
__device__ __forceinline__ float gelu_tanh(float x) {
  float x3 = x*x*x;
  return 0.5f*x*(1.0f + tanhf(0.7978845608028654f*(x + 0.044715f*x3)));
}

// ---------------- embedding + sinusoidal PE ----------------
__global__ __launch_bounds__(256) void k_embed(
    const int* __restrict__ ta, const int* __restrict__ tb, const int* __restrict__ tp,
    const float* __restrict__ Wa, const float* __restrict__ Wb, const float* __restrict__ Wp,
    float* __restrict__ X) {
  int idx = blockIdx.x * 256 + threadIdx.x;
  if (idx >= NB*NS*DM) return;
  int d = idx & (DM-1);
  int bs = idx >> 9;
  int s = bs % NS, b = bs / NS;
  int sl, tok; const float* W;
  if (s < SSA)          { sl = s;         tok = ta[b*SSA+sl]; W = Wa; }
  else if (s < SSA+SSB) { sl = s-SSA;     tok = tb[b*SSB+sl]; W = Wb; }
  else                  { sl = s-SSA-SSB; tok = tp[b*SSP+sl]; W = Wp; }
  float dv = expf((float)(d & ~1) * (-9.210340371976184f/512.0f));
  float ang = (float)sl * dv;
  float pe = (d & 1) ? cosf(ang) : sinf(ang);
  X[idx] = W[(size_t)tok*DM + d] + pe;
}

// ---------------- split-bf16 (bf16x3) MFMA GEMM, 128x128 tile, BK=32 ----------------
// fp32-grade accuracy: A,B staged as hi+lo bf16; 3 MFMA per fragment pair.
// AM=0: A f32 at Ap[(bi*pitch + roff + sl)*lda + k],  bi=m/rpg, sl=m%rpg
// AM=1: A f32 head-layout: (m,c) at Ap[((bi*8 + (c>>6))*seg + sl)*64 + (c&63)]
// CM=0: C f32 at Cp[(bi*pitch + roff + sl)*ldc + n]  (guard n<N)
// CM=1: C f32 QKV head-layout: j=n>>9 (q/k/v), Cp[j*qst + ((bi*8+h)*seg+sl)*64 + d]
template<int AM, int CM>
__global__ __launch_bounds__(256) void k_mfma(
    const float* __restrict__ Ap, const float* __restrict__ Bp, float* __restrict__ Cp,
    int N, int K, int lda, int ldb, int ldc,
    int rpg, int pitch, int roff, int seg,
    long long bstride, int bshift, long long qst) {
  __shared__ short Ah[128][40], Al[128][40], Bh[128][40], Bl[128][40];
  int t = threadIdx.x;
  int m0 = blockIdx.x * 128, n0 = blockIdx.y * 128;
  int w = t >> 6, lane = t & 63;
  int wm = w >> 1, wn = w & 1;
  int tq = t & 7, tr = t >> 3;            // A staging: k-quad(0..7), row(0..31)
  int abi[4], asl[4];
#pragma unroll
  for (int p = 0; p < 4; p++) {
    int m = m0 + tr + p*32;
    abi[p] = m / rpg;
    asl[p] = m - abi[p]*rpg;
  }
  int bn = t & 127, bkh = t >> 7;         // B staging: col(0..127), k-half(0..1)
  int gn = n0 + bn;
  const float* Bcol = nullptr;
  if (gn < N) {
    int j = gn >> bshift;
    int col = gn - (j << bshift);
    Bcol = Bp + (long long)j * bstride + col;
  }
  f32x4 acc[4][4];
#pragma unroll
  for (int i = 0; i < 4; i++)
#pragma unroll
    for (int j = 0; j < 4; j++) acc[i][j] = (f32x4){0.f,0.f,0.f,0.f};

  for (int k0 = 0; k0 < K; k0 += 32) {
    // ---- stage A (hi/lo) ----
#pragma unroll
    for (int p = 0; p < 4; p++) {
      int row = tr + p*32;
      float4 v;
      if (AM == 0) {
        v = *(const float4*)&Ap[(size_t)(abi[p]*pitch + roff + asl[p])*lda + k0 + tq*4];
      } else {
        int c = k0 + tq*4;
        int hh = c >> 6, dd = c & 63;
        v = *(const float4*)&Ap[((size_t)(abi[p]*8 + hh)*seg + asl[p])*64 + dd];
      }
      s16x4 hv, lv;
      unsigned int p0 = split_bf(v.x), p1 = split_bf(v.y), p2 = split_bf(v.z), p3 = split_bf(v.w);
      hv[0] = (short)(p0 & 0xffffu); lv[0] = (short)(p0 >> 16);
      hv[1] = (short)(p1 & 0xffffu); lv[1] = (short)(p1 >> 16);
      hv[2] = (short)(p2 & 0xffffu); lv[2] = (short)(p2 >> 16);
      hv[3] = (short)(p3 & 0xffffu); lv[3] = (short)(p3 >> 16);
      *(s16x4*)&Ah[row][tq*4] = hv;
      *(s16x4*)&Al[row][tq*4] = lv;
    }
    // ---- stage B (hi/lo) ----
    {
      s16x8 h0, h1v, l0, l1v;
#pragma unroll
      for (int kk = 0; kk < 8; kk++) {
        float v0 = Bcol ? Bcol[(size_t)(k0 + bkh*16 + kk)*ldb] : 0.f;
        float v1 = Bcol ? Bcol[(size_t)(k0 + bkh*16 + 8 + kk)*ldb] : 0.f;
        unsigned int q0 = split_bf(v0), q1 = split_bf(v1);
        h0[kk]  = (short)(q0 & 0xffffu); l0[kk]  = (short)(q0 >> 16);
        h1v[kk] = (short)(q1 & 0xffffu); l1v[kk] = (short)(q1 >> 16);
      }
      *(s16x8*)&Bh[bn][bkh*16]     = h0;
      *(s16x8*)&Bh[bn][bkh*16 + 8] = h1v;
      *(s16x8*)&Bl[bn][bkh*16]     = l0;
      *(s16x8*)&Bl[bn][bkh*16 + 8] = l1v;
    }
    __syncthreads();
    s16x8 ahf[4], alf[4], bhf[4], blf[4];
#pragma unroll
    for (int fm = 0; fm < 4; fm++) {
      int r = wm*64 + fm*16 + (lane & 15);
      int cofs = (lane >> 4)*8;
      ahf[fm] = *(const s16x8*)&Ah[r][cofs];
      alf[fm] = *(const s16x8*)&Al[r][cofs];
    }
#pragma unroll
    for (int fn = 0; fn < 4; fn++) {
      int r = wn*64 + fn*16 + (lane & 15);
      int cofs = (lane >> 4)*8;
      bhf[fn] = *(const s16x8*)&Bh[r][cofs];
      blf[fn] = *(const s16x8*)&Bl[r][cofs];
    }
#pragma unroll
    for (int fm = 0; fm < 4; fm++)
#pragma unroll
      for (int fn = 0; fn < 4; fn++) {
        acc[fm][fn] = __builtin_amdgcn_mfma_f32_16x16x32_bf16(ahf[fm], bhf[fn], acc[fm][fn], 0, 0, 0);
        acc[fm][fn] = __builtin_amdgcn_mfma_f32_16x16x32_bf16(alf[fm], bhf[fn], acc[fm][fn], 0, 0, 0);
        acc[fm][fn] = __builtin_amdgcn_mfma_f32_16x16x32_bf16(ahf[fm], blf[fn], acc[fm][fn], 0, 0, 0);
      }
    __syncthreads();
  }
  // ---- epilogue ----
#pragma unroll
  for (int fm = 0; fm < 4; fm++) {
#pragma unroll
    for (int jj = 0; jj < 4; jj++) {
      int mrow = m0 + wm*64 + fm*16 + (lane >> 4)*4 + jj;
      int bi = mrow / rpg, sl = mrow - bi*rpg;
#pragma unroll
      for (int fn = 0; fn < 4; fn++) {
        int ncol = n0 + wn*64 + fn*16 + (lane & 15);
        float vv = acc[fm][fn][jj];
        if (CM == 0) {
          if (ncol < N) Cp[(size_t)(bi*pitch + roff + sl)*ldc + ncol] = vv;
        } else {
          int j = ncol >> 9, rem = ncol & 511;
          int hh = rem >> 6, dd = rem & 63;
          Cp[(long long)j*qst + ((size_t)(bi*8 + hh)*seg + sl)*64 + dd] = vv;
        }
      }
    }
  }
}

// ---------------- attention core per (b,h): f32 QKV, out overwrites Q slice ----------------
__global__ __launch_bounds__(256) void k_attn2(
    float* __restrict__ Qb, const float* __restrict__ Kb, const float* __restrict__ Vb, int seg) {
  __shared__ float Qs[NS][65], Ks[NS][65], Vs[NS][65];
  __shared__ float pb[4][128];
  int b = blockIdx.x, h = blockIdx.y;
  size_t base = ((size_t)(b*8 + h)) * seg * 64;
  int t = threadIdx.x, w = t >> 6, lane = t & 63;
  for (int i = t; i < seg*64; i += 256) {
    int r = i >> 6, d = i & 63;
    Qs[r][d] = Qb[base + i];
    Ks[r][d] = Kb[base + i];
    Vs[r][d] = Vb[base + i];
  }
  __syncthreads();
  for (int qi = w; qi < seg; qi += 4) {
    float s1 = -1e30f, s2 = -1e30f;
    int j1 = lane, j2 = lane + 64;
    if (j1 < seg) {
      float acc = 0.f;
#pragma unroll
      for (int d = 0; d < DH; d++) acc += Qs[qi][d]*Ks[j1][d];
      s1 = acc * 0.125f;
    }
    if (j2 < seg) {
      float acc = 0.f;
#pragma unroll
      for (int d = 0; d < DH; d++) acc += Qs[qi][d]*Ks[j2][d];
      s2 = acc * 0.125f;
    }
    float m = fmaxf(s1, s2);
#pragma unroll
    for (int o = 32; o; o >>= 1) m = fmaxf(m, __shfl_xor(m, o));
    float p1 = (j1 < seg) ? expf(s1 - m) : 0.f;
    float p2 = (j2 < seg) ? expf(s2 - m) : 0.f;
    float l = p1 + p2;
#pragma unroll
    for (int o = 32; o; o >>= 1) l += __shfl_xor(l, o);
    float inv = 1.f / l;
    pb[w][lane] = p1 * inv;
    pb[w][lane + 64] = p2 * inv;
    float o = 0.f;
    for (int j = 0; j < seg; j++) o += pb[w][j] * Vs[j][lane];
    Qb[base + (size_t)qi*64 + lane] = o;
  }
}

// ---------------- residual add + RMSNorm; U rows (per-branch) -> X rows ----------------
__global__ __launch_bounds__(256) void k_addnorm(
    float* __restrict__ X, const float* __restrict__ U, const float* __restrict__ w,
    int seg, int boff) {
  int r = blockIdx.x, t = threadIdx.x;
  int b = r / seg, s = r - b*seg;
  size_t xb = ((size_t)b*NS + boff + s)*DM;
  size_t ub = (size_t)r*DM;
  float v0 = X[xb+t] + U[ub+t];
  float v1 = X[xb+t+256] + U[ub+t+256];
  float ss = v0*v0 + v1*v1;
#pragma unroll
  for (int o = 32; o; o >>= 1) ss += __shfl_xor(ss, o);
  __shared__ float red[4];
  if ((t & 63) == 0) red[t>>6] = ss;
  __syncthreads();
  float tot = red[0]+red[1]+red[2]+red[3];
  float sc = rsqrtf(tot * (1.f/512.f) + 1e-6f);
  X[xb+t] = v0*sc*w[t];
  X[xb+t+256] = v1*sc*w[t+256];
}

// ---------------- MoE routing (fp32, round-1 numerics) ----------------
__global__ __launch_bounds__(256) void k_route(
    const float* __restrict__ X, const float* __restrict__ Wg,
    int* __restrict__ rec_src, float* __restrict__ rec_gain, int* __restrict__ cnt) {
  __shared__ float gl[NS][NE];
  __shared__ float g1s[NS], g2s[NS];
  __shared__ int i1s[NS], i2s[NS];
  int b = blockIdx.x, t = threadIdx.x;
  for (int e0 = t; e0 < NS*NE; e0 += 256) {
    int s = e0 >> 4, ee = e0 & 15;
    const float* xr = X + ((size_t)b*NS + s)*DM;
    float acc = 0.f;
    for (int k = 0; k < DM; k++) acc += xr[k]*Wg[k*NE+ee];
    gl[s][ee] = acc;
  }
  __syncthreads();
  if (t < NS) {
    float mx = -1e30f;
#pragma unroll
    for (int e = 0; e < NE; e++) mx = fmaxf(mx, gl[t][e]);
    float sum = 0.f;
#pragma unroll
    for (int e = 0; e < NE; e++) sum += expf(gl[t][e]-mx);
    int i1 = 0; float l1 = gl[t][0];
#pragma unroll
    for (int e = 1; e < NE; e++) if (gl[t][e] > l1) { l1 = gl[t][e]; i1 = e; }
    int i2 = -1; float l2 = -1e30f;
#pragma unroll
    for (int e = 0; e < NE; e++) if (e != i1 && gl[t][e] > l2) { l2 = gl[t][e]; i2 = e; }
    float g1 = expf(l1-mx)/sum, g2 = expf(l2-mx)/sum;
    float den = g1 + g2 + 1e-9f;
    g1s[t] = g1/den; g2s[t] = g2/den;
    i1s[t] = i1; i2s[t] = i2;
  }
  __syncthreads();
  if (t == 0) {
    int n1[NE], n2[NE], c1[NE];
    for (int e = 0; e < NE; e++) { n1[e]=0; n2[e]=0; }
    for (int s = 0; s < NS; s++) {
      int e = i1s[s]; int p = n1[e]++;
      if (p < CAP) {
        int idx = atomicAdd(&cnt[e*2+0], 1);
        rec_src[(size_t)(e*2+0)*NSLOT + idx] = b*NS + s;
        rec_gain[(size_t)(e*2+0)*NSLOT + idx] = g1s[s];
      }
    }
    for (int e = 0; e < NE; e++) c1[e] = n1[e] < CAP ? n1[e] : CAP;
    for (int s = 0; s < NS; s++) {
      int e = i2s[s]; int p = c1[e] + n2[e]++;
      if (p < CAP) {
        int idx = atomicAdd(&cnt[e*2+1], 1);
        rec_src[(size_t)(e*2+1)*NSLOT + idx] = b*NS + s;
        rec_gain[(size_t)(e*2+1)*NSLOT + idx] = g2s[s];
      }
    }
  }
}

// ---------------- expert MLP over compacted rows (fp32), accumulate into Y ----------------
__global__ __launch_bounds__(256) void k_expert(
    const float* __restrict__ X, const float* __restrict__ W1,
    const float* __restrict__ W2, float* __restrict__ Y,
    const int* __restrict__ rec_src, const float* __restrict__ rec_gain,
    const int* __restrict__ cnt, int rank) {
  int e = blockIdx.y;
  int l = e*2 + rank;
  int n = cnt[l];
  int r0 = blockIdx.x * 32;
  if (r0 >= n) return;
  __shared__ float Xs[32][DM];
  __shared__ int srcs[32];
  __shared__ float gains[32];
  int t = threadIdx.x;
  if (t < 32) {
    int rr = r0 + t;
    srcs[t]  = (rr < n) ? rec_src [(size_t)l*NSLOT + rr] : -1;
    gains[t] = (rr < n) ? rec_gain[(size_t)l*NSLOT + rr] : 0.f;
  }
  __syncthreads();
  for (int r = 0; r < 32; r++) {
    int src = srcs[r];
    float v0 = 0.f, v1 = 0.f;
    if (src >= 0) {
      v0 = X[(size_t)src*DM + t];
      v1 = X[(size_t)src*DM + t + 256];
    }
    Xs[r][t] = v0; Xs[r][t+256] = v1;
  }
  __syncthreads();
  const float* w1 = W1 + (size_t)e*DM*DM;
  float a0[32], a1[32];
#pragma unroll
  for (int r = 0; r < 32; r++) { a0[r]=0.f; a1[r]=0.f; }
  for (int k0 = 0; k0 < DM; k0 += 4) {
    float wa[4], wb[4];
#pragma unroll
    for (int q = 0; q < 4; q++) { wa[q] = w1[(size_t)(k0+q)*DM + t]; wb[q] = w1[(size_t)(k0+q)*DM + t+256]; }
#pragma unroll
    for (int r = 0; r < 32; r++) {
      float4 x = *reinterpret_cast<const float4*>(&Xs[r][k0]);
      a0[r] += x.x*wa[0] + x.y*wa[1] + x.z*wa[2] + x.w*wa[3];
      a1[r] += x.x*wb[0] + x.y*wb[1] + x.z*wb[2] + x.w*wb[3];
    }
  }
  __syncthreads();
#pragma unroll
  for (int r = 0; r < 32; r++) {
    Xs[r][t]     = gelu_tanh(a0[r]);
    Xs[r][t+256] = gelu_tanh(a1[r]);
  }
  __syncthreads();
  const float* w2 = W2 + (size_t)e*DM*DM;
#pragma unroll
  for (int r = 0; r < 32; r++) { a0[r]=0.f; a1[r]=0.f; }
  for (int k0 = 0; k0 < DM; k0 += 4) {
    float wa[4], wb[4];
#pragma unroll
    for (int q = 0; q < 4; q++) { wa[q] = w2[(size_t)(k0+q)*DM + t]; wb[q] = w2[(size_t)(k0+q)*DM + t+256]; }
#pragma unroll
    for (int r = 0; r < 32; r++) {
      float4 x = *reinterpret_cast<const float4*>(&Xs[r][k0]);
      a0[r] += x.x*wa[0] + x.y*wa[1] + x.z*wa[2] + x.w*wa[3];
      a1[r] += x.x*wb[0] + x.y*wb[1] + x.z*wb[2] + x.w*wb[3];
    }
  }
  for (int r = 0; r < 32; r++) {
    int src = srcs[r];
    if (src >= 0) {
      float g = gains[r];
      size_t base = (size_t)src*DM;
      Y[base+t]     += g*a0[r];
      Y[base+t+256] += g*a1[r];
    }
  }
}

// ---------------- classifier epilogue ----------------
__global__ __launch_bounds__(256) void k_h1norm(
    float* __restrict__ H, const float* __restrict__ bias, const float* __restrict__ w) {
  int r = blockIdx.x, t = threadIdx.x;
  size_t base = (size_t)r*1000;
  float v[4]; float ss = 0.f;
#pragma unroll
  for (int i = 0; i < 4; i++) {
    int c = t + i*256;
    float x = 0.f;
    if (c < 1000) { x = fmaxf(H[base+c] + bias[c], 0.f); }
    v[i] = x; ss += x*x;
  }
#pragma unroll
  for (int o = 32; o; o >>= 1) ss += __shfl_xor(ss, o);
  __shared__ float red[4];
  if ((t & 63) == 0) red[t>>6] = ss;
  __syncthreads();
  float tot = red[0]+red[1]+red[2]+red[3];
  float sc = rsqrtf(tot * 0.001f + 1e-6f);
#pragma unroll
  for (int i = 0; i < 4; i++) {
    int c = t + i*256;
    if (c < 1000) H[base+c] = v[i]*sc*w[c];
  }
}

__global__ __launch_bounds__(128) void k_h2(
    const float* __restrict__ H1, const float* __restrict__ W2c,
    const float* __restrict__ b2, const float* __restrict__ rms2,
    float* __restrict__ H2) {
  __shared__ float hrow[1000];
  __shared__ float sq[128];
  int r = blockIdx.x, t = threadIdx.x;
  for (int c = t; c < 1000; c += 128) hrow[c] = H1[(size_t)r*1000+c];
  __syncthreads();
  float acc = 0.f;
  if (t < 100) {
    for (int k = 0; k < 1000; k++) acc += hrow[k]*W2c[k*100+t];
    acc = fmaxf(acc + b2[t], 0.f);
  }
  sq[t] = (t < 100) ? acc*acc : 0.f;
  __syncthreads();
  if (t < 64) sq[t] += sq[t+64];
  __syncthreads();
  if (t == 0) { float s = 0.f; for (int i = 0; i < 64; i++) s += sq[i]; sq[0] = s; }
  __syncthreads();
  float sc = rsqrtf(sq[0]*0.01f + 1e-6f);
  if (t < 100) H2[(size_t)r*100+t] = acc*sc*rms2[t];
}

__global__ __launch_bounds__(256) void k_out(
    const float* __restrict__ H2, const float* __restrict__ w3,
    const float* __restrict__ b3, float* __restrict__ out) {
  int b = blockIdx.x*256 + threadIdx.x;
  if (b >= NB) return;
  float acc = b3[0];
  for (int k = 0; k < 100; k++) acc += H2[(size_t)b*100+k]*w3[k];
  out[b] = acc;
}

extern "C" void kernel_launch(void* const* d_in, const int* in_sizes, int n_in,
                              void* d_out, int out_size, void* d_ws, size_t ws_size,
                              hipStream_t stream) {
  const int*   ta   = (const int*)d_in[0];
  const int*   tb   = (const int*)d_in[1];
  const int*   tp   = (const int*)d_in[2];
  const float* Wa   = (const float*)d_in[3];
  const float* Wb   = (const float*)d_in[4];
  const float* Wp   = (const float*)d_in[5];
  const float* AW   = (const float*)d_in[6];
  const float* rmsd = (const float*)d_in[7];
  const float* Wg   = (const float*)d_in[8];
  const float* W1   = (const float*)d_in[9];
  const float* W2   = (const float*)d_in[10];
  const float* cw1  = (const float*)d_in[11];
  const float* cb1  = (const float*)d_in[12];
  const float* rms1 = (const float*)d_in[13];
  const float* cw2  = (const float*)d_in[14];
  const float* cb2  = (const float*)d_in[15];
  const float* rms2 = (const float*)d_in[16];
  const float* cw3  = (const float*)d_in[17];
  const float* cb3  = (const float*)d_in[18];
  float* out = (float*)d_out;

  const size_t NELM = (size_t)NB*NS*DM;          // 39,845,888
  const size_t WMAT = (size_t)DM*DM;             // 262144
  const long long QSTA = (long long)NB*SSA*DM;   // 17,825,792 (branch-A Q/K/V stride)

  char* ws = (char*)d_ws;
  float* X  = (float*)ws;                                   // 159.4 MB residual stream
  float* Q0 = (float*)(ws + NELM*sizeof(float));            // 214 MB QKV scratch region
  char*  tail = (char*)Q0 + (size_t)3*QSTA*sizeof(float);
  int*   rec_src  = (int*)tail;
  float* rec_gain = (float*)(tail + (size_t)NE*2*NSLOT*4);
  int*   cnt      = (int*)(tail + (size_t)NE*2*NSLOT*8);
  float* h1       = (float*)(tail + (size_t)NE*2*NSLOT*8 + 256);
  float* h2       = h1 + (size_t)NB*1000;
  float* Y        = Q0;                                     // MoE stream aliases QKV scratch

  // 1. embedding + PE -> X
  k_embed<<<dim3((NB*NS*DM+255)/256), 256, 0, stream>>>(ta,tb,tp,Wa,Wb,Wp,X);

  // 2-4. per-branch encoders (sequential through Q0 scratch)
  const int segs[3]  = {SSA, SSB, SSP};
  const int boffs[3] = {0, SSA, SSA+SSB};
  for (int br = 0; br < 3; br++) {
    int seg = segs[br], boff = boffs[br];
    int M = NB*seg;
    long long qst = (long long)M*DM;
    float* Qr = Q0; float* Kr = Q0 + qst; float* Vr = Q0 + 2*qst;
    // QKV (N=1536 fused) -> head-layout f32
    k_mfma<0,1><<<dim3(M/128,12),256,0,stream>>>(X, AW + (size_t)br*4*WMAT, Q0,
        1536,512, 512,512,0,  seg,NS,boff,seg, (long long)WMAT,9, qst);
    // attention (out overwrites Q slice)
    k_attn2<<<dim3(NB,NH),256,0,stream>>>(Qr, Kr, Vr, seg);
    // O-proj: A = attn-out (Q region), C -> V region
    k_mfma<1,0><<<dim3(M/128,4),256,0,stream>>>(Qr, AW + (size_t)(br*4+3)*WMAT, Vr,
        512,512, 0,512,512,  seg,seg,0,seg, 0,30, 0);
    // residual + RMSNorm -> X
    k_addnorm<<<M,256,0,stream>>>(X, Vr, rmsd, seg, boff);
  }

  // 5. full-sequence encoder, 4 batch-chunks of 256
  {
    const int CH = 256;
    int M = CH*NS;                       // 19456
    long long qst = (long long)M*DM;
    float* Qr = Q0; float* Kr = Q0 + qst; float* Vr = Q0 + 2*qst;
    for (int c = 0; c < 4; c++) {
      float* Xc = X + (size_t)c*CH*NS*DM;
      k_mfma<0,1><<<dim3(M/128,12),256,0,stream>>>(Xc, AW + (size_t)12*WMAT, Q0,
          1536,512, 512,512,0,  NS,NS,0,NS, (long long)WMAT,9, qst);
      k_attn2<<<dim3(CH,NH),256,0,stream>>>(Qr, Kr, Vr, NS);
      k_mfma<1,0><<<dim3(M/128,4),256,0,stream>>>(Qr, AW + (size_t)15*WMAT, Vr,
          512,512, 0,512,512,  NS,NS,0,NS, 0,30, 0);
      k_addnorm<<<M,256,0,stream>>>(Xc, Vr, rmsd, NS, 0);
    }
  }

  // 6. MoE
  hipError_t e1 = hipMemsetAsync(cnt, 0, NE*2*sizeof(int), stream); (void)e1;
  k_route<<<NB,256,0,stream>>>(X, Wg, rec_src, rec_gain, cnt);
  hipError_t e2 = hipMemcpyAsync(Y, X, NELM*sizeof(float), hipMemcpyDeviceToDevice, stream); (void)e2;
  k_expert<<<dim3((NSLOT+31)/32, NE),256,0,stream>>>(X, W1, W2, Y, rec_src, rec_gain, cnt, 0);
  k_expert<<<dim3((NSLOT+31)/32, NE),256,0,stream>>>(X, W1, W2, Y, rec_src, rec_gain, cnt, 1);

  // 7. classifier
  k_mfma<0,0><<<dim3(NB/128,(1000+127)/128),256,0,stream>>>(Y, cw1, h1,
      1000,NS*DM, NS*DM,1000,1000,  NB,0,0,1, 0,30, 0);
  k_h1norm<<<NB,256,0,stream>>>(h1, cb1, rms1);
  k_h2<<<NB,128,0,stream>>>(h1, cw2, cb2, rms2, h2);
  k_out<<<dim3((NB+255)/256),256,0,stream>>>(h2, cw3, cb3, out);
}

// Round 5
// 7283.910 us; speedup vs baseline: 5.7238x; 1.4045x over previous
//
#include <hip/hip_runtime.h>
#include <math.h>

#define NB 1024
#define NS 76
#define SSA 34
#define SSB 28
#define SSP 14
#define DM 512
#define NH 8
#define DH 64
#define NE 16
#define CAP 19
#define NSLOT (NB*CAP)
#define KSPLIT 8

typedef unsigned short ushortt;
typedef short s16x4 __attribute__((ext_vector_type(4)));
typedef short s16x8 __attribute__((ext_vector_type(8)));
typedef float f32x4 __attribute__((ext_vector_type(4)));

__device__ __forceinline__ ushortt f2bf(float f) {
  union { float f; unsigned int u; } v; v.f = f;
  unsigned int u = v.u;
  u += 0x7fffu + ((u >> 16) & 1u);
  return (ushortt)(u >> 16);
}
__device__ __forceinline__ float bf2f(ushortt s) {
  union { unsigned int u; float f; } v; v.u = ((unsigned int)s) << 16;
  return v.f;
}
// returns lo<<16 | hi  (hi = bf16(v), lo = bf16(v - hi))
__device__ __forceinline__ unsigned int split_bf(float v) {
  ushortt h = f2bf(v);
  float r = v - bf2f(h);
  ushortt l = f2bf(r);
  return ((unsigned int)l << 16) | (unsigned int)h;
}
__device__ __forceinline__ float gelu_tanh(float x) {
  float x3 = x*x*x;
  return 0.5f*x*(1.0f + tanhf(0.7978845608028654f*(x + 0.044715f*x3)));
}

// ---------------- embedding + sinusoidal PE ----------------
__global__ __launch_bounds__(256) void k_embed(
    const int* __restrict__ ta, const int* __restrict__ tb, const int* __restrict__ tp,
    const float* __restrict__ Wa, const float* __restrict__ Wb, const float* __restrict__ Wp,
    float* __restrict__ X) {
  int idx = blockIdx.x * 256 + threadIdx.x;
  if (idx >= NB*NS*DM) return;
  int d = idx & (DM-1);
  int bs = idx >> 9;
  int s = bs % NS, b = bs / NS;
  int sl, tok; const float* W;
  if (s < SSA)          { sl = s;         tok = ta[b*SSA+sl]; W = Wa; }
  else if (s < SSA+SSB) { sl = s-SSA;     tok = tb[b*SSB+sl]; W = Wb; }
  else                  { sl = s-SSA-SSB; tok = tp[b*SSP+sl]; W = Wp; }
  float dv = expf((float)(d & ~1) * (-9.210340371976184f/512.0f));
  float ang = (float)sl * dv;
  float pe = (d & 1) ? cosf(ang) : sinf(ang);
  X[idx] = W[(size_t)tok*DM + d] + pe;
}

// ---------------- weight pre-split: f32 -> packed (lo16|hi16) ----------------
__global__ __launch_bounds__(256) void k_split_arr(
    const float* __restrict__ in, unsigned int* __restrict__ out, int n) {
  int i = blockIdx.x * 256 + threadIdx.x;
  if (i < n) out[i] = split_bf(in[i]);
}

// ---------------- split-bf16 (bf16x3) MFMA GEMM, 128x128 tile, BK=32 ----------------
// AM=0: A f32 at Ap[(bi*pitch + roff + sl)*lda + koff + k], bi=m/rpg, sl=m%rpg
// AM=1: A f32 head-layout: (m,c) at Ap[((bi*8 + (c>>6))*seg + sl)*64 + (c&63)]
// BS=1: B is pre-split packed uint32; BS=0: B is f32, split on the fly
// CM=0: C f32 at Cp[kz*csplit + (bi*pitch + roff + sl)*ldc + n]  (guard n<N)
// CM=1: C f32 QKV head-layout: j=n>>9 (q/k/v), Cp[j*qst + ((bi*8+h)*seg+sl)*64 + d]
// blockIdx.z = K-split index kz; chunk size = K (arg), A/B offset koff = kz*K.
template<int AM, int CM, int BS>
__global__ __launch_bounds__(256) void k_mfma(
    const float* __restrict__ Ap, const void* __restrict__ Bpv, float* __restrict__ Cp,
    int N, int K, int lda, int ldb, int ldc,
    int rpg, int pitch, int roff, int seg,
    long long bstride, int bshift, long long qst, long long csplit) {
  __shared__ short Ah[128][40], Al[128][40], Bh[128][40], Bl[128][40];
  int t = threadIdx.x;
  int m0 = blockIdx.x * 128, n0 = blockIdx.y * 128;
  int kz = blockIdx.z;
  long long koff = (long long)kz * K;
  int w = t >> 6, lane = t & 63;
  int wm = w >> 1, wn = w & 1;
  int tq = t & 7, tr = t >> 3;            // A staging: k-quad(0..7), row(0..31)
  int abi[4], asl[4];
#pragma unroll
  for (int p = 0; p < 4; p++) {
    int m = m0 + tr + p*32;
    abi[p] = m / rpg;
    asl[p] = m - abi[p]*rpg;
  }
  int bn = t & 127, bkh = t >> 7;         // B staging: col(0..127), k-half(0..1)
  int gn = n0 + bn;
  const float* Bcolf = nullptr;
  const unsigned int* Bcolu = nullptr;
  if (gn < N) {
    int j = gn >> bshift;
    int col = gn - (j << bshift);
    if (BS) Bcolu = (const unsigned int*)Bpv + (long long)j*bstride + col + koff*ldb;
    else    Bcolf = (const float*)Bpv + (long long)j*bstride + col + koff*ldb;
  }
  f32x4 acc[4][4];
#pragma unroll
  for (int i = 0; i < 4; i++)
#pragma unroll
    for (int j = 0; j < 4; j++) acc[i][j] = (f32x4){0.f,0.f,0.f,0.f};

  for (int k0 = 0; k0 < K; k0 += 32) {
    // ---- stage A (hi/lo) ----
#pragma unroll
    for (int p = 0; p < 4; p++) {
      int row = tr + p*32;
      float4 v;
      if (AM == 0) {
        v = *(const float4*)&Ap[(size_t)(abi[p]*pitch + roff + asl[p])*lda + (size_t)koff + k0 + tq*4];
      } else {
        int c = k0 + tq*4;
        int hh = c >> 6, dd = c & 63;
        v = *(const float4*)&Ap[((size_t)(abi[p]*8 + hh)*seg + asl[p])*64 + dd];
      }
      s16x4 hv, lv;
      unsigned int p0 = split_bf(v.x), p1 = split_bf(v.y), p2 = split_bf(v.z), p3 = split_bf(v.w);
      hv[0] = (short)(p0 & 0xffffu); lv[0] = (short)(p0 >> 16);
      hv[1] = (short)(p1 & 0xffffu); lv[1] = (short)(p1 >> 16);
      hv[2] = (short)(p2 & 0xffffu); lv[2] = (short)(p2 >> 16);
      hv[3] = (short)(p3 & 0xffffu); lv[3] = (short)(p3 >> 16);
      *(s16x4*)&Ah[row][tq*4] = hv;
      *(s16x4*)&Al[row][tq*4] = lv;
    }
    // ---- stage B (hi/lo) ----
    {
      s16x8 h0, h1v, l0, l1v;
#pragma unroll
      for (int kk = 0; kk < 8; kk++) {
        unsigned int q0, q1;
        if (BS) {
          q0 = Bcolu ? Bcolu[(size_t)(k0 + bkh*16 + kk)*ldb] : 0u;
          q1 = Bcolu ? Bcolu[(size_t)(k0 + bkh*16 + 8 + kk)*ldb] : 0u;
        } else {
          q0 = Bcolf ? split_bf(Bcolf[(size_t)(k0 + bkh*16 + kk)*ldb]) : 0u;
          q1 = Bcolf ? split_bf(Bcolf[(size_t)(k0 + bkh*16 + 8 + kk)*ldb]) : 0u;
        }
        h0[kk]  = (short)(q0 & 0xffffu); l0[kk]  = (short)(q0 >> 16);
        h1v[kk] = (short)(q1 & 0xffffu); l1v[kk] = (short)(q1 >> 16);
      }
      *(s16x8*)&Bh[bn][bkh*16]     = h0;
      *(s16x8*)&Bh[bn][bkh*16 + 8] = h1v;
      *(s16x8*)&Bl[bn][bkh*16]     = l0;
      *(s16x8*)&Bl[bn][bkh*16 + 8] = l1v;
    }
    __syncthreads();
    s16x8 ahf[4], alf[4], bhf[4], blf[4];
#pragma unroll
    for (int fm = 0; fm < 4; fm++) {
      int r = wm*64 + fm*16 + (lane & 15);
      int cofs = (lane >> 4)*8;
      ahf[fm] = *(const s16x8*)&Ah[r][cofs];
      alf[fm] = *(const s16x8*)&Al[r][cofs];
    }
#pragma unroll
    for (int fn = 0; fn < 4; fn++) {
      int r = wn*64 + fn*16 + (lane & 15);
      int cofs = (lane >> 4)*8;
      bhf[fn] = *(const s16x8*)&Bh[r][cofs];
      blf[fn] = *(const s16x8*)&Bl[r][cofs];
    }
#pragma unroll
    for (int fm = 0; fm < 4; fm++)
#pragma unroll
      for (int fn = 0; fn < 4; fn++) {
        acc[fm][fn] = __builtin_amdgcn_mfma_f32_16x16x32_bf16(ahf[fm], bhf[fn], acc[fm][fn], 0, 0, 0);
        acc[fm][fn] = __builtin_amdgcn_mfma_f32_16x16x32_bf16(alf[fm], bhf[fn], acc[fm][fn], 0, 0, 0);
        acc[fm][fn] = __builtin_amdgcn_mfma_f32_16x16x32_bf16(ahf[fm], blf[fn], acc[fm][fn], 0, 0, 0);
      }
    __syncthreads();
  }
  // ---- epilogue ----
#pragma unroll
  for (int fm = 0; fm < 4; fm++) {
#pragma unroll
    for (int jj = 0; jj < 4; jj++) {
      int mrow = m0 + wm*64 + fm*16 + (lane >> 4)*4 + jj;
      int bi = mrow / rpg, sl = mrow - bi*rpg;
#pragma unroll
      for (int fn = 0; fn < 4; fn++) {
        int ncol = n0 + wn*64 + fn*16 + (lane & 15);
        float vv = acc[fm][fn][jj];
        if (CM == 0) {
          if (ncol < N) Cp[(long long)kz*csplit + (size_t)(bi*pitch + roff + sl)*ldc + ncol] = vv;
        } else {
          int j = ncol >> 9, rem = ncol & 511;
          int hh = rem >> 6, dd = rem & 63;
          Cp[(long long)j*qst + ((size_t)(bi*8 + hh)*seg + sl)*64 + dd] = vv;
        }
      }
    }
  }
}

// ---------------- k-split reduce: h1[i] = sum_z P[z][i] ----------------
__global__ __launch_bounds__(256) void k_ksum(
    const float* __restrict__ P, float* __restrict__ h1) {
  int i = blockIdx.x * 256 + threadIdx.x;
  if (i >= NB*1000) return;
  float s = 0.f;
#pragma unroll
  for (int z = 0; z < KSPLIT; z++) s += P[(size_t)z*NB*1000 + i];
  h1[i] = s;
}

// ---------------- attention core per (b,h): f32 QKV, out overwrites Q slice ----------------
__global__ __launch_bounds__(256) void k_attn2(
    float* __restrict__ Qb, const float* __restrict__ Kb, const float* __restrict__ Vb, int seg) {
  __shared__ float Qs[NS][65], Ks[NS][65], Vs[NS][65];
  __shared__ float pb[4][128];
  int b = blockIdx.x, h = blockIdx.y;
  size_t base = ((size_t)(b*8 + h)) * seg * 64;
  int t = threadIdx.x, w = t >> 6, lane = t & 63;
  for (int i = t; i < seg*64; i += 256) {
    int r = i >> 6, d = i & 63;
    Qs[r][d] = Qb[base + i];
    Ks[r][d] = Kb[base + i];
    Vs[r][d] = Vb[base + i];
  }
  __syncthreads();
  for (int qi = w; qi < seg; qi += 4) {
    float s1 = -1e30f, s2 = -1e30f;
    int j1 = lane, j2 = lane + 64;
    if (j1 < seg) {
      float acc = 0.f;
#pragma unroll
      for (int d = 0; d < DH; d++) acc += Qs[qi][d]*Ks[j1][d];
      s1 = acc * 0.125f;
    }
    if (j2 < seg) {
      float acc = 0.f;
#pragma unroll
      for (int d = 0; d < DH; d++) acc += Qs[qi][d]*Ks[j2][d];
      s2 = acc * 0.125f;
    }
    float m = fmaxf(s1, s2);
#pragma unroll
    for (int o = 32; o; o >>= 1) m = fmaxf(m, __shfl_xor(m, o));
    float p1 = (j1 < seg) ? expf(s1 - m) : 0.f;
    float p2 = (j2 < seg) ? expf(s2 - m) : 0.f;
    float l = p1 + p2;
#pragma unroll
    for (int o = 32; o; o >>= 1) l += __shfl_xor(l, o);
    float inv = 1.f / l;
    pb[w][lane] = p1 * inv;
    pb[w][lane + 64] = p2 * inv;
    float o = 0.f;
    for (int j = 0; j < seg; j++) o += pb[w][j] * Vs[j][lane];
    Qb[base + (size_t)qi*64 + lane] = o;
  }
}

// ---------------- residual add + RMSNorm; U rows (per-branch) -> X rows ----------------
__global__ __launch_bounds__(256) void k_addnorm(
    float* __restrict__ X, const float* __restrict__ U, const float* __restrict__ w,
    int seg, int boff) {
  int r = blockIdx.x, t = threadIdx.x;
  int b = r / seg, s = r - b*seg;
  size_t xb = ((size_t)b*NS + boff + s)*DM;
  size_t ub = (size_t)r*DM;
  float v0 = X[xb+t] + U[ub+t];
  float v1 = X[xb+t+256] + U[ub+t+256];
  float ss = v0*v0 + v1*v1;
#pragma unroll
  for (int o = 32; o; o >>= 1) ss += __shfl_xor(ss, o);
  __shared__ float red[4];
  if ((t & 63) == 0) red[t>>6] = ss;
  __syncthreads();
  float tot = red[0]+red[1]+red[2]+red[3];
  float sc = rsqrtf(tot * (1.f/512.f) + 1e-6f);
  X[xb+t] = v0*sc*w[t];
  X[xb+t+256] = v1*sc*w[t+256];
}

// ---------------- MoE routing (fp32, round-1 numerics) ----------------
__global__ __launch_bounds__(256) void k_route(
    const float* __restrict__ X, const float* __restrict__ Wg,
    int* __restrict__ rec_src, float* __restrict__ rec_gain, int* __restrict__ cnt) {
  __shared__ float gl[NS][NE];
  __shared__ float g1s[NS], g2s[NS];
  __shared__ int i1s[NS], i2s[NS];
  int b = blockIdx.x, t = threadIdx.x;
  for (int e0 = t; e0 < NS*NE; e0 += 256) {
    int s = e0 >> 4, ee = e0 & 15;
    const float* xr = X + ((size_t)b*NS + s)*DM;
    float acc = 0.f;
    for (int k = 0; k < DM; k++) acc += xr[k]*Wg[k*NE+ee];
    gl[s][ee] = acc;
  }
  __syncthreads();
  if (t < NS) {
    float mx = -1e30f;
#pragma unroll
    for (int e = 0; e < NE; e++) mx = fmaxf(mx, gl[t][e]);
    float sum = 0.f;
#pragma unroll
    for (int e = 0; e < NE; e++) sum += expf(gl[t][e]-mx);
    int i1 = 0; float l1 = gl[t][0];
#pragma unroll
    for (int e = 1; e < NE; e++) if (gl[t][e] > l1) { l1 = gl[t][e]; i1 = e; }
    int i2 = -1; float l2 = -1e30f;
#pragma unroll
    for (int e = 0; e < NE; e++) if (e != i1 && gl[t][e] > l2) { l2 = gl[t][e]; i2 = e; }
    float g1 = expf(l1-mx)/sum, g2 = expf(l2-mx)/sum;
    float den = g1 + g2 + 1e-9f;
    g1s[t] = g1/den; g2s[t] = g2/den;
    i1s[t] = i1; i2s[t] = i2;
  }
  __syncthreads();
  if (t == 0) {
    int n1[NE], n2[NE], c1[NE];
    for (int e = 0; e < NE; e++) { n1[e]=0; n2[e]=0; }
    for (int s = 0; s < NS; s++) {
      int e = i1s[s]; int p = n1[e]++;
      if (p < CAP) {
        int idx = atomicAdd(&cnt[e*2+0], 1);
        rec_src[(size_t)(e*2+0)*NSLOT + idx] = b*NS + s;
        rec_gain[(size_t)(e*2+0)*NSLOT + idx] = g1s[s];
      }
    }
    for (int e = 0; e < NE; e++) c1[e] = n1[e] < CAP ? n1[e] : CAP;
    for (int s = 0; s < NS; s++) {
      int e = i2s[s]; int p = c1[e] + n2[e]++;
      if (p < CAP) {
        int idx = atomicAdd(&cnt[e*2+1], 1);
        rec_src[(size_t)(e*2+1)*NSLOT + idx] = b*NS + s;
        rec_gain[(size_t)(e*2+1)*NSLOT + idx] = g2s[s];
      }
    }
  }
}

// ---------------- fused expert MLP (split-bf16 MFMA), 64-row list tiles ----------------
// hid kept in LDS f32 (padded 516 to break bank conflicts). Y[src] += gain*out.
__global__ __launch_bounds__(256, 1) void k_expert_mfma(
    const float* __restrict__ X, const unsigned int* __restrict__ W1s,
    const unsigned int* __restrict__ W2s, float* __restrict__ Y,
    const int* __restrict__ rec_src, const float* __restrict__ rec_gain,
    const int* __restrict__ cnt, int rank) {
  __shared__ float hid[64][516];
  __shared__ short Ah[64][40], Al[64][40];
  __shared__ short Bh[128][40], Bl[128][40];
  __shared__ int srcs[64];
  __shared__ float gains[64];
  int e = blockIdx.y;
  int l = e*2 + rank;
  int nrows = cnt[l];
  int r0 = blockIdx.x * 64;
  if (r0 >= nrows) return;
  int t = threadIdx.x;
  int w = t >> 6, lane = t & 63;
  int wm = w >> 1, wn = w & 1;
  if (t < 64) {
    int rr = r0 + t;
    srcs[t]  = (rr < nrows) ? rec_src [(size_t)l*NSLOT + rr] : -1;
    gains[t] = (rr < nrows) ? rec_gain[(size_t)l*NSLOT + rr] : 0.f;
  }
  __syncthreads();
  const unsigned int* w1 = W1s + (size_t)e*DM*DM;
  const unsigned int* w2 = W2s + (size_t)e*DM*DM;
  int tr = t >> 2, tq = t & 3;        // A staging: row(0..63), k-oct(0..3) of 8
  int bn = t & 127, bkh = t >> 7;     // B staging: col(0..127), k-half(0..1)
  int mysrc = srcs[tr];

  // ================= layer 1: hid = gelu(x @ w1) =================
  for (int n0 = 0; n0 < 512; n0 += 128) {
    f32x4 acc[2][4];
#pragma unroll
    for (int i = 0; i < 2; i++)
#pragma unroll
      for (int j = 0; j < 4; j++) acc[i][j] = (f32x4){0.f,0.f,0.f,0.f};
    for (int k0 = 0; k0 < 512; k0 += 32) {
      // A stage (gathered X rows)
      {
        float4 v0 = {0.f,0.f,0.f,0.f}, v1 = {0.f,0.f,0.f,0.f};
        if (mysrc >= 0) {
          const float* xr = X + (size_t)mysrc*DM + k0 + tq*8;
          v0 = *(const float4*)xr;
          v1 = *(const float4*)(xr + 4);
        }
        s16x4 hv, lv;
        unsigned int p0 = split_bf(v0.x), p1 = split_bf(v0.y), p2 = split_bf(v0.z), p3 = split_bf(v0.w);
        hv[0]=(short)(p0&0xffffu); lv[0]=(short)(p0>>16);
        hv[1]=(short)(p1&0xffffu); lv[1]=(short)(p1>>16);
        hv[2]=(short)(p2&0xffffu); lv[2]=(short)(p2>>16);
        hv[3]=(short)(p3&0xffffu); lv[3]=(short)(p3>>16);
        *(s16x4*)&Ah[tr][tq*8] = hv; *(s16x4*)&Al[tr][tq*8] = lv;
        p0 = split_bf(v1.x); p1 = split_bf(v1.y); p2 = split_bf(v1.z); p3 = split_bf(v1.w);
        hv[0]=(short)(p0&0xffffu); lv[0]=(short)(p0>>16);
        hv[1]=(short)(p1&0xffffu); lv[1]=(short)(p1>>16);
        hv[2]=(short)(p2&0xffffu); lv[2]=(short)(p2>>16);
        hv[3]=(short)(p3&0xffffu); lv[3]=(short)(p3>>16);
        *(s16x4*)&Ah[tr][tq*8+4] = hv; *(s16x4*)&Al[tr][tq*8+4] = lv;
      }
      // B stage (pre-split w1)
      {
        s16x8 h0, h1v, l0, l1v;
#pragma unroll
        for (int kk = 0; kk < 8; kk++) {
          unsigned int q0 = w1[(size_t)(k0 + bkh*16 + kk)*DM + n0 + bn];
          unsigned int q1 = w1[(size_t)(k0 + bkh*16 + 8 + kk)*DM + n0 + bn];
          h0[kk]  = (short)(q0 & 0xffffu); l0[kk]  = (short)(q0 >> 16);
          h1v[kk] = (short)(q1 & 0xffffu); l1v[kk] = (short)(q1 >> 16);
        }
        *(s16x8*)&Bh[bn][bkh*16]   = h0;  *(s16x8*)&Bh[bn][bkh*16+8] = h1v;
        *(s16x8*)&Bl[bn][bkh*16]   = l0;  *(s16x8*)&Bl[bn][bkh*16+8] = l1v;
      }
      __syncthreads();
      s16x8 ahf[2], alf[2], bhf[4], blf[4];
#pragma unroll
      for (int fm = 0; fm < 2; fm++) {
        int r = wm*32 + fm*16 + (lane & 15);
        int cofs = (lane >> 4)*8;
        ahf[fm] = *(const s16x8*)&Ah[r][cofs];
        alf[fm] = *(const s16x8*)&Al[r][cofs];
      }
#pragma unroll
      for (int fn = 0; fn < 4; fn++) {
        int r = wn*64 + fn*16 + (lane & 15);
        int cofs = (lane >> 4)*8;
        bhf[fn] = *(const s16x8*)&Bh[r][cofs];
        blf[fn] = *(const s16x8*)&Bl[r][cofs];
      }
#pragma unroll
      for (int fm = 0; fm < 2; fm++)
#pragma unroll
        for (int fn = 0; fn < 4; fn++) {
          acc[fm][fn] = __builtin_amdgcn_mfma_f32_16x16x32_bf16(ahf[fm], bhf[fn], acc[fm][fn], 0, 0, 0);
          acc[fm][fn] = __builtin_amdgcn_mfma_f32_16x16x32_bf16(alf[fm], bhf[fn], acc[fm][fn], 0, 0, 0);
          acc[fm][fn] = __builtin_amdgcn_mfma_f32_16x16x32_bf16(ahf[fm], blf[fn], acc[fm][fn], 0, 0, 0);
        }
      __syncthreads();
    }
    // epilogue -> gelu -> hid
#pragma unroll
    for (int fm = 0; fm < 2; fm++)
#pragma unroll
      for (int jj = 0; jj < 4; jj++) {
        int row = wm*32 + fm*16 + (lane >> 4)*4 + jj;
#pragma unroll
        for (int fn = 0; fn < 4; fn++) {
          int col = n0 + wn*64 + fn*16 + (lane & 15);
          hid[row][col] = gelu_tanh(acc[fm][fn][jj]);
        }
      }
  }
  __syncthreads();

  // ================= layer 2: out = hid @ w2; Y[src] += gain*out =================
  for (int n0 = 0; n0 < 512; n0 += 128) {
    f32x4 acc[2][4];
#pragma unroll
    for (int i = 0; i < 2; i++)
#pragma unroll
      for (int j = 0; j < 4; j++) acc[i][j] = (f32x4){0.f,0.f,0.f,0.f};
    for (int k0 = 0; k0 < 512; k0 += 32) {
      // A stage from hid (LDS f32 -> split)
      {
        s16x4 hv, lv;
        float a0 = hid[tr][k0+tq*8+0], a1 = hid[tr][k0+tq*8+1];
        float a2 = hid[tr][k0+tq*8+2], a3 = hid[tr][k0+tq*8+3];
        unsigned int p0 = split_bf(a0), p1 = split_bf(a1), p2 = split_bf(a2), p3 = split_bf(a3);
        hv[0]=(short)(p0&0xffffu); lv[0]=(short)(p0>>16);
        hv[1]=(short)(p1&0xffffu); lv[1]=(short)(p1>>16);
        hv[2]=(short)(p2&0xffffu); lv[2]=(short)(p2>>16);
        hv[3]=(short)(p3&0xffffu); lv[3]=(short)(p3>>16);
        *(s16x4*)&Ah[tr][tq*8] = hv; *(s16x4*)&Al[tr][tq*8] = lv;
        a0 = hid[tr][k0+tq*8+4]; a1 = hid[tr][k0+tq*8+5];
        a2 = hid[tr][k0+tq*8+6]; a3 = hid[tr][k0+tq*8+7];
        p0 = split_bf(a0); p1 = split_bf(a1); p2 = split_bf(a2); p3 = split_bf(a3);
        hv[0]=(short)(p0&0xffffu); lv[0]=(short)(p0>>16);
        hv[1]=(short)(p1&0xffffu); lv[1]=(short)(p1>>16);
        hv[2]=(short)(p2&0xffffu); lv[2]=(short)(p2>>16);
        hv[3]=(short)(p3&0xffffu); lv[3]=(short)(p3>>16);
        *(s16x4*)&Ah[tr][tq*8+4] = hv; *(s16x4*)&Al[tr][tq*8+4] = lv;
      }
      // B stage (pre-split w2)
      {
        s16x8 h0, h1v, l0, l1v;
#pragma unroll
        for (int kk = 0; kk < 8; kk++) {
          unsigned int q0 = w2[(size_t)(k0 + bkh*16 + kk)*DM + n0 + bn];
          unsigned int q1 = w2[(size_t)(k0 + bkh*16 + 8 + kk)*DM + n0 + bn];
          h0[kk]  = (short)(q0 & 0xffffu); l0[kk]  = (short)(q0 >> 16);
          h1v[kk] = (short)(q1 & 0xffffu); l1v[kk] = (short)(q1 >> 16);
        }
        *(s16x8*)&Bh[bn][bkh*16]   = h0;  *(s16x8*)&Bh[bn][bkh*16+8] = h1v;
        *(s16x8*)&Bl[bn][bkh*16]   = l0;  *(s16x8*)&Bl[bn][bkh*16+8] = l1v;
      }
      __syncthreads();
      s16x8 ahf[2], alf[2], bhf[4], blf[4];
#pragma unroll
      for (int fm = 0; fm < 2; fm++) {
        int r = wm*32 + fm*16 + (lane & 15);
        int cofs = (lane >> 4)*8;
        ahf[fm] = *(const s16x8*)&Ah[r][cofs];
        alf[fm] = *(const s16x8*)&Al[r][cofs];
      }
#pragma unroll
      for (int fn = 0; fn < 4; fn++) {
        int r = wn*64 + fn*16 + (lane & 15);
        int cofs = (lane >> 4)*8;
        bhf[fn] = *(const s16x8*)&Bh[r][cofs];
        blf[fn] = *(const s16x8*)&Bl[r][cofs];
      }
#pragma unroll
      for (int fm = 0; fm < 2; fm++)
#pragma unroll
        for (int fn = 0; fn < 4; fn++) {
          acc[fm][fn] = __builtin_amdgcn_mfma_f32_16x16x32_bf16(ahf[fm], bhf[fn], acc[fm][fn], 0, 0, 0);
          acc[fm][fn] = __builtin_amdgcn_mfma_f32_16x16x32_bf16(alf[fm], bhf[fn], acc[fm][fn], 0, 0, 0);
          acc[fm][fn] = __builtin_amdgcn_mfma_f32_16x16x32_bf16(ahf[fm], blf[fn], acc[fm][fn], 0, 0, 0);
        }
      __syncthreads();
    }
    // scatter epilogue
#pragma unroll
    for (int fm = 0; fm < 2; fm++)
#pragma unroll
      for (int jj = 0; jj < 4; jj++) {
        int row = wm*32 + fm*16 + (lane >> 4)*4 + jj;
        int src = srcs[row];
        float g = gains[row];
        if (src >= 0) {
#pragma unroll
          for (int fn = 0; fn < 4; fn++) {
            int col = n0 + wn*64 + fn*16 + (lane & 15);
            Y[(size_t)src*DM + col] += g * acc[fm][fn][jj];
          }
        }
      }
  }
}

// ---------------- classifier epilogue ----------------
__global__ __launch_bounds__(256) void k_h1norm(
    float* __restrict__ H, const float* __restrict__ bias, const float* __restrict__ w) {
  int r = blockIdx.x, t = threadIdx.x;
  size_t base = (size_t)r*1000;
  float v[4]; float ss = 0.f;
#pragma unroll
  for (int i = 0; i < 4; i++) {
    int c = t + i*256;
    float x = 0.f;
    if (c < 1000) { x = fmaxf(H[base+c] + bias[c], 0.f); }
    v[i] = x; ss += x*x;
  }
#pragma unroll
  for (int o = 32; o; o >>= 1) ss += __shfl_xor(ss, o);
  __shared__ float red[4];
  if ((t & 63) == 0) red[t>>6] = ss;
  __syncthreads();
  float tot = red[0]+red[1]+red[2]+red[3];
  float sc = rsqrtf(tot * 0.001f + 1e-6f);
#pragma unroll
  for (int i = 0; i < 4; i++) {
    int c = t + i*256;
    if (c < 1000) H[base+c] = v[i]*sc*w[c];
  }
}

__global__ __launch_bounds__(128) void k_h2(
    const float* __restrict__ H1, const float* __restrict__ W2c,
    const float* __restrict__ b2, const float* __restrict__ rms2,
    float* __restrict__ H2) {
  __shared__ float hrow[1000];
  __shared__ float sq[128];
  int r = blockIdx.x, t = threadIdx.x;
  for (int c = t; c < 1000; c += 128) hrow[c] = H1[(size_t)r*1000+c];
  __syncthreads();
  float acc = 0.f;
  if (t < 100) {
    for (int k = 0; k < 1000; k++) acc += hrow[k]*W2c[k*100+t];
    acc = fmaxf(acc + b2[t], 0.f);
  }
  sq[t] = (t < 100) ? acc*acc : 0.f;
  __syncthreads();
  if (t < 64) sq[t] += sq[t+64];
  __syncthreads();
  if (t == 0) { float s = 0.f; for (int i = 0; i < 64; i++) s += sq[i]; sq[0] = s; }
  __syncthreads();
  float sc = rsqrtf(sq[0]*0.01f + 1e-6f);
  if (t < 100) H2[(size_t)r*100+t] = acc*sc*rms2[t];
}

__global__ __launch_bounds__(256) void k_out(
    const float* __restrict__ H2, const float* __restrict__ w3,
    const float* __restrict__ b3, float* __restrict__ out) {
  int b = blockIdx.x*256 + threadIdx.x;
  if (b >= NB) return;
  float acc = b3[0];
  for (int k = 0; k < 100; k++) acc += H2[(size_t)b*100+k]*w3[k];
  out[b] = acc;
}

extern "C" void kernel_launch(void* const* d_in, const int* in_sizes, int n_in,
                              void* d_out, int out_size, void* d_ws, size_t ws_size,
                              hipStream_t stream) {
  const int*   ta   = (const int*)d_in[0];
  const int*   tb   = (const int*)d_in[1];
  const int*   tp   = (const int*)d_in[2];
  const float* Wa   = (const float*)d_in[3];
  const float* Wb   = (const float*)d_in[4];
  const float* Wp   = (const float*)d_in[5];
  const float* AW   = (const float*)d_in[6];
  const float* rmsd = (const float*)d_in[7];
  const float* Wg   = (const float*)d_in[8];
  const float* W1   = (const float*)d_in[9];
  const float* W2   = (const float*)d_in[10];
  const float* cw1  = (const float*)d_in[11];
  const float* cb1  = (const float*)d_in[12];
  const float* rms1 = (const float*)d_in[13];
  const float* cw2  = (const float*)d_in[14];
  const float* cb2  = (const float*)d_in[15];
  const float* rms2 = (const float*)d_in[16];
  const float* cw3  = (const float*)d_in[17];
  const float* cb3  = (const float*)d_in[18];
  float* out = (float*)d_out;

  const size_t NELM = (size_t)NB*NS*DM;          // 39,845,888
  const size_t WMAT = (size_t)DM*DM;             // 262144
  const long long QSTA = (long long)NB*SSA*DM;   // branch-A Q/K/V stride

  char* ws = (char*)d_ws;
  float* X  = (float*)ws;                                   // 159.4 MB residual stream
  float* Q0 = (float*)(ws + NELM*sizeof(float));            // 214 MB QKV scratch region
  char*  tail = (char*)Q0 + (size_t)3*QSTA*sizeof(float);
  int*   rec_src  = (int*)tail;
  float* rec_gain = (float*)(tail + (size_t)NE*2*NSLOT*4);
  int*   cnt      = (int*)(tail + (size_t)NE*2*NSLOT*8);
  float* h1       = (float*)(tail + (size_t)NE*2*NSLOT*8 + 256);
  float* h2       = h1 + (size_t)NB*1000;
  float* P        = h2 + (size_t)NB*100;                    // [KSPLIT][1024][1000]
  unsigned int* AWs = (unsigned int*)(P + (size_t)KSPLIT*NB*1000);
  unsigned int* W1s = AWs + (size_t)16*WMAT;
  unsigned int* W2s = W1s + (size_t)16*WMAT;
  float* Y        = Q0;                                     // MoE stream aliases QKV scratch

  // 0. pre-split weights (AW, W1, W2) -> packed hi/lo
  k_split_arr<<<dim3((16*WMAT+255)/256), 256, 0, stream>>>(AW, AWs, 16*WMAT);
  k_split_arr<<<dim3((16*WMAT+255)/256), 256, 0, stream>>>(W1, W1s, 16*WMAT);
  k_split_arr<<<dim3((16*WMAT+255)/256), 256, 0, stream>>>(W2, W2s, 16*WMAT);

  // 1. embedding + PE -> X
  k_embed<<<dim3((NB*NS*DM+255)/256), 256, 0, stream>>>(ta,tb,tp,Wa,Wb,Wp,X);

  // 2-4. per-branch encoders (sequential through Q0 scratch)
  const int segs[3]  = {SSA, SSB, SSP};
  const int boffs[3] = {0, SSA, SSA+SSB};
  for (int br = 0; br < 3; br++) {
    int seg = segs[br], boff = boffs[br];
    int M = NB*seg;
    long long qst = (long long)M*DM;
    float* Qr = Q0; float* Kr = Q0 + qst; float* Vr = Q0 + 2*qst;
    k_mfma<0,1,1><<<dim3(M/128,12,1),256,0,stream>>>(X, AWs + (size_t)br*4*WMAT, Q0,
        1536,512, 512,512,0,  seg,NS,boff,seg, (long long)WMAT,9, qst, 0);
    k_attn2<<<dim3(NB,NH),256,0,stream>>>(Qr, Kr, Vr, seg);
    k_mfma<1,0,1><<<dim3(M/128,4,1),256,0,stream>>>(Qr, AWs + (size_t)(br*4+3)*WMAT, Vr,
        512,512, 0,512,512,  seg,seg,0,seg, 0,30, 0, 0);
    k_addnorm<<<M,256,0,stream>>>(X, Vr, rmsd, seg, boff);
  }

  // 5. full-sequence encoder, 4 batch-chunks of 256
  {
    const int CH = 256;
    int M = CH*NS;                       // 19456
    long long qst = (long long)M*DM;
    float* Qr = Q0; float* Kr = Q0 + qst; float* Vr = Q0 + 2*qst;
    for (int c = 0; c < 4; c++) {
      float* Xc = X + (size_t)c*CH*NS*DM;
      k_mfma<0,1,1><<<dim3(M/128,12,1),256,0,stream>>>(Xc, AWs + (size_t)12*WMAT, Q0,
          1536,512, 512,512,0,  NS,NS,0,NS, (long long)WMAT,9, qst, 0);
      k_attn2<<<dim3(CH,NH),256,0,stream>>>(Qr, Kr, Vr, NS);
      k_mfma<1,0,1><<<dim3(M/128,4,1),256,0,stream>>>(Qr, AWs + (size_t)15*WMAT, Vr,
          512,512, 0,512,512,  NS,NS,0,NS, 0,30, 0, 0);
      k_addnorm<<<M,256,0,stream>>>(Xc, Vr, rmsd, NS, 0);
    }
  }

  // 6. MoE
  hipError_t e1 = hipMemsetAsync(cnt, 0, NE*2*sizeof(int), stream); (void)e1;
  k_route<<<NB,256,0,stream>>>(X, Wg, rec_src, rec_gain, cnt);
  hipError_t e2 = hipMemcpyAsync(Y, X, NELM*sizeof(float), hipMemcpyDeviceToDevice, stream); (void)e2;
  k_expert_mfma<<<dim3((NSLOT+63)/64, NE),256,0,stream>>>(X, W1s, W2s, Y, rec_src, rec_gain, cnt, 0);
  k_expert_mfma<<<dim3((NSLOT+63)/64, NE),256,0,stream>>>(X, W1s, W2s, Y, rec_src, rec_gain, cnt, 1);

  // 7. classifier: split-K GEMM -> P, reduce -> h1, epilogue
  k_mfma<0,0,0><<<dim3(NB/128,(1000+127)/128,KSPLIT),256,0,stream>>>(Y, cw1, P,
      1000, (NS*DM)/KSPLIT, NS*DM,1000,1000,  NB,0,0,1, 0,30, 0, (long long)NB*1000);
  k_ksum<<<dim3((NB*1000+255)/256),256,0,stream>>>(P, h1);
  k_h1norm<<<NB,256,0,stream>>>(h1, cb1, rms1);
  k_h2<<<NB,128,0,stream>>>(h1, cw2, cb2, rms2, h2);
  k_out<<<dim3((NB+255)/256),256,0,stream>>>(h2, cw3, cb3, out);
}